// Round 1
// baseline (428.129 us; speedup 1.0000x reference)
//
#include <hip/hip_runtime.h>
#include <hip/hip_bf16.h>

#define N_PIX 2304
#define C_IN  256
#define INNER 384
#define HEADS 8
#define HDIM  48
#define DPAD  64
#define SCALE 0.14433756729740643f
#define LOG2E 1.44269504088896341f

typedef __bf16 bf16x8 __attribute__((ext_vector_type(8)));
typedef float  f32x4  __attribute__((ext_vector_type(4)));
typedef short  s16x8  __attribute__((ext_vector_type(8)));

union Frag { s16x8 s; bf16x8 b; };

__device__ inline short f2bf_bits(float f){
  union { float f; unsigned u; } v; v.f = f;
  unsigned r = v.u + 0x7fffu + ((v.u >> 16) & 1u);
  return (short)(r >> 16);
}

// ---------------- GroupNorm stats: one block per (b,g) ----------------
__global__ __launch_bounds__(256) void gn_stats(const float* __restrict__ x,
                                                float* __restrict__ mu,
                                                float* __restrict__ rs){
  int bg = blockIdx.x;                       // b*32+g ; channels of a group are contiguous
  const float* p = x + (size_t)bg * 8 * N_PIX;
  float s = 0.f, s2 = 0.f;
  for (int i = threadIdx.x; i < 8 * N_PIX; i += 256){
    float v = p[i]; s += v; s2 += v * v;
  }
  __shared__ float ls[256], ls2[256];
  ls[threadIdx.x] = s; ls2[threadIdx.x] = s2;
  __syncthreads();
  for (int off = 128; off > 0; off >>= 1){
    if ((int)threadIdx.x < off){ ls[threadIdx.x] += ls[threadIdx.x + off]; ls2[threadIdx.x] += ls2[threadIdx.x + off]; }
    __syncthreads();
  }
  if (threadIdx.x == 0){
    float m = ls[0] / 18432.f;
    float var = ls2[0] / 18432.f - m * m;
    mu[bg] = m; rs[bg] = rsqrtf(var + 1e-5f);
  }
}

// ---- Q/K projection: rows=n, cols=o.  OUT[b,h,n,64] (pad cols stay 0 via memset) ----
__global__ __launch_bounds__(256) void proj_qk(const float* __restrict__ X,
                                               const float* __restrict__ W,
                                               const float* __restrict__ bias,
                                               const float* __restrict__ gnw,
                                               const float* __restrict__ gnb,
                                               const float* __restrict__ mu,
                                               const float* __restrict__ rs,
                                               short* __restrict__ OUT, int useGN){
  int b = blockIdx.z, nb = blockIdx.x * 64, ob = blockIdx.y * 64;
  int wave = threadIdx.x >> 6, lane = threadIdx.x & 63;
  int l16 = lane & 15, lq = lane >> 4;
  int o0 = ob + wave * 16;

  f32x4 acc[4] = {};
  for (int k = 0; k < 8; ++k){
    Frag wf;                                  // B = W^T : lane holds W[o0+l16][k32+lq8+u] (contig)
    const float* wp = W + (size_t)(o0 + l16) * C_IN + k * 32 + lq * 8;
    #pragma unroll
    for (int u = 0; u < 8; ++u) wf.s[u] = f2bf_bits(wp[u]);
    #pragma unroll
    for (int nt = 0; nt < 4; ++nt){
      int n = nb + nt * 16 + l16;
      Frag af;                                // A = X^T : row n, k=c (strided global)
      #pragma unroll
      for (int u = 0; u < 8; ++u){
        int c = k * 32 + lq * 8 + u;
        float v = X[((size_t)b * C_IN + c) * N_PIX + n];
        if (useGN){
          int bg = b * 32 + (c >> 3);
          v = (v - mu[bg]) * rs[bg] * gnw[c] + gnb[c];
        }
        af.s[u] = f2bf_bits(v);
      }
      acc[nt] = __builtin_amdgcn_mfma_f32_16x16x32_bf16(af.b, wf.b, acc[nt], 0, 0, 0);
    }
  }
  int o = o0 + l16;
  int h = (o * 683) >> 15;                    // o/48 for o<384
  int d = o - h * 48;
  float bv = bias[o];
  #pragma unroll
  for (int nt = 0; nt < 4; ++nt)
    #pragma unroll
    for (int r = 0; r < 4; ++r){
      int n = nb + nt * 16 + lq * 4 + r;
      OUT[(((size_t)b * HEADS + h) * N_PIX + n) * DPAD + d] = f2bf_bits(acc[nt][r] + bv);
    }
}

// ---- V projection: rows=o, cols=n.  VT[b,h,d,n]  (transposed for PV B-frags) ----
__global__ __launch_bounds__(256) void proj_v(const float* __restrict__ X,
                                              const float* __restrict__ W,
                                              const float* __restrict__ bias,
                                              short* __restrict__ VT){
  int b = blockIdx.z, nb = blockIdx.x * 64, ob = blockIdx.y * 64;
  int wave = threadIdx.x >> 6, lane = threadIdx.x & 63;
  int l16 = lane & 15, lq = lane >> 4;
  int o0 = ob + wave * 16;

  f32x4 acc[4] = {};
  for (int k = 0; k < 8; ++k){
    Frag wf;                                  // A = W : row o, k=c (contig)
    const float* wp = W + (size_t)(o0 + l16) * C_IN + k * 32 + lq * 8;
    #pragma unroll
    for (int u = 0; u < 8; ++u) wf.s[u] = f2bf_bits(wp[u]);
    #pragma unroll
    for (int nt = 0; nt < 4; ++nt){
      Frag xf;                                // B = X : k=c, col n (strided global)
      #pragma unroll
      for (int u = 0; u < 8; ++u){
        int c = k * 32 + lq * 8 + u;
        xf.s[u] = f2bf_bits(X[((size_t)b * C_IN + c) * N_PIX + nb + nt * 16 + l16]);
      }
      acc[nt] = __builtin_amdgcn_mfma_f32_16x16x32_bf16(wf.b, xf.b, acc[nt], 0, 0, 0);
    }
  }
  #pragma unroll
  for (int r = 0; r < 4; ++r){
    int o = o0 + lq * 4 + r;
    int h = (o * 683) >> 15;
    int d = o - h * 48;
    float bv = bias[o];
    #pragma unroll
    for (int nt = 0; nt < 4; ++nt){
      int n = nb + nt * 16 + l16;
      VT[(((size_t)b * HEADS + h) * DPAD + d) * N_PIX + n] = f2bf_bits(acc[nt][r] + bv);
    }
  }
}

// ---------------- Flash attention: block = 64 q-rows, 4 waves x 16 rows ----------------
__global__ __launch_bounds__(256) void attn_kernel(const short* __restrict__ Q,
                                                   const short* __restrict__ K,
                                                   const short* __restrict__ VT,
                                                   short* __restrict__ AOUT){
  int bh = blockIdx.y;
  int b = bh >> 3, h = bh & 7;
  int ib = blockIdx.x * 64;
  int wave = threadIdx.x >> 6, lane = threadIdx.x & 63;
  int l16 = lane & 15, lq = lane >> 4;
  int qrow = ib + wave * 16;

  __shared__ __align__(16) short kt[64 * 64];       // K tile [j][d], XOR-swizzled
  __shared__ __align__(16) short vt[64 * 64];       // V tile [d][j], XOR-swizzled
  __shared__ __align__(16) short pt[4][16 * 64];    // per-wave P tile, XOR-swizzled

  Frag qf[2];
  {
    const short* qp = Q + ((size_t)bh * N_PIX + qrow + l16) * DPAD;
    qf[0].s = *(const s16x8*)(qp + lq * 8);
    qf[1].s = *(const s16x8*)(qp + 32 + lq * 8);
  }

  float mrow[4], lrow[4];
  f32x4 oacc[3] = {};
  #pragma unroll
  for (int r = 0; r < 4; ++r){ mrow[r] = -1e30f; lrow[r] = 0.f; }

  for (int jt = 0; jt < N_PIX / 64; ++jt){
    __syncthreads();
    #pragma unroll
    for (int it = 0; it < 2; ++it){             // stage K and Vt tiles, 16B/thread/iter
      int idx = threadIdx.x + it * 256;
      int row = idx >> 3, cb = idx & 7;
      int scb = cb ^ (row & 7);
      *(s16x8*)(kt + row * 64 + scb * 8) =
        *(const s16x8*)(K + ((size_t)bh * N_PIX + jt * 64 + row) * DPAD + cb * 8);
      *(s16x8*)(vt + row * 64 + scb * 8) =
        *(const s16x8*)(VT + ((size_t)bh * DPAD + row) * N_PIX + jt * 64 + cb * 8);
    }
    __syncthreads();

    // S = Q K^T  (4 col-tiles of 16, 2 k-steps of 32; d 48..63 are zero-padded in Q)
    f32x4 s[4] = {};
    #pragma unroll
    for (int ct = 0; ct < 4; ++ct){
      int krow = ct * 16 + l16;
      #pragma unroll
      for (int kk = 0; kk < 2; ++kk){
        Frag kf;
        kf.s = *(const s16x8*)(kt + krow * 64 + ((kk * 4 + lq) ^ (krow & 7)) * 8);
        s[ct] = __builtin_amdgcn_mfma_f32_16x16x32_bf16(qf[kk].b, kf.b, s[ct], 0, 0, 0);
      }
    }

    // online softmax (rows live on 16-lane groups: row = lq*4+r)
    #pragma unroll
    for (int r = 0; r < 4; ++r){
      float mx = fmaxf(fmaxf(s[0][r], s[1][r]), fmaxf(s[2][r], s[3][r])) * SCALE;
      #pragma unroll
      for (int d = 1; d < 16; d <<= 1) mx = fmaxf(mx, __shfl_xor(mx, d));
      float mnew = fmaxf(mrow[r], mx);
      float corr = exp2f((mrow[r] - mnew) * LOG2E);
      mrow[r] = mnew;
      float psum = 0.f;
      #pragma unroll
      for (int ct = 0; ct < 4; ++ct){
        float p = exp2f((s[ct][r] * SCALE - mnew) * LOG2E);
        s[ct][r] = p; psum += p;
      }
      #pragma unroll
      for (int d = 1; d < 16; d <<= 1) psum += __shfl_xor(psum, d);
      lrow[r] = lrow[r] * corr + psum;
      #pragma unroll
      for (int dt = 0; dt < 3; ++dt) oacc[dt][r] *= corr;
    }

    // P -> per-wave LDS (transpose S-frag layout into A-frag layout)
    short* pw = &pt[wave][0];
    #pragma unroll
    for (int ct = 0; ct < 4; ++ct)
      #pragma unroll
      for (int r = 0; r < 4; ++r){
        int row = lq * 4 + r, col = ct * 16 + l16;
        pw[row * 64 + (col ^ ((row & 7) << 3))] = f2bf_bits(s[ct][r]);
      }

    // O += P V   (3 d-tiles of 16 -> d<48 only; V pad rows never read)
    #pragma unroll
    for (int kk = 0; kk < 2; ++kk){
      Frag pf;
      pf.s = *(const s16x8*)(pw + l16 * 64 + ((kk * 4 + lq) ^ (l16 & 7)) * 8);
      #pragma unroll
      for (int dt = 0; dt < 3; ++dt){
        int vrow = dt * 16 + l16;
        Frag vf;
        vf.s = *(const s16x8*)(vt + vrow * 64 + ((kk * 4 + lq) ^ (vrow & 7)) * 8);
        oacc[dt] = __builtin_amdgcn_mfma_f32_16x16x32_bf16(pf.b, vf.b, oacc[dt], 0, 0, 0);
      }
    }
  }

  #pragma unroll
  for (int r = 0; r < 4; ++r){
    float inv = 1.f / lrow[r];
    int n = qrow + lq * 4 + r;
    #pragma unroll
    for (int dt = 0; dt < 3; ++dt)
      AOUT[((size_t)b * N_PIX + n) * INNER + h * HDIM + dt * 16 + l16] =
        f2bf_bits(oacc[dt][r] * inv);
  }
}

// ---- Output projection + bias + residual: rows=o, cols=n; both frags contiguous ----
__global__ __launch_bounds__(256) void proj_o(const float* __restrict__ WO,
                                              const float* __restrict__ BO,
                                              const short* __restrict__ AOUT,
                                              const float* __restrict__ RES,
                                              float* __restrict__ OUT){
  int b = blockIdx.z, nb = blockIdx.x * 64, ob = blockIdx.y * 64;
  int wave = threadIdx.x >> 6, lane = threadIdx.x & 63;
  int l16 = lane & 15, lq = lane >> 4;
  int o0 = ob + wave * 16;

  f32x4 acc[4] = {};
  for (int k = 0; k < 12; ++k){
    Frag wf;                                  // A = WO : row o, contig k
    const float* wp = WO + (size_t)(o0 + l16) * INNER + k * 32 + lq * 8;
    #pragma unroll
    for (int u = 0; u < 8; ++u) wf.s[u] = f2bf_bits(wp[u]);
    #pragma unroll
    for (int nt = 0; nt < 4; ++nt){
      Frag af;                                // B = AOUT^T : lane reads aout[n][i..i+8) contig bf16
      af.s = *(const s16x8*)(AOUT + ((size_t)b * N_PIX + nb + nt * 16 + l16) * INNER + k * 32 + lq * 8);
      acc[nt] = __builtin_amdgcn_mfma_f32_16x16x32_bf16(wf.b, af.b, acc[nt], 0, 0, 0);
    }
  }
  #pragma unroll
  for (int r = 0; r < 4; ++r){
    int o = o0 + lq * 4 + r;
    float bv = BO[o];
    #pragma unroll
    for (int nt = 0; nt < 4; ++nt){
      int n = nb + nt * 16 + l16;
      size_t idx = ((size_t)b * C_IN + o) * N_PIX + n;
      OUT[idx] = acc[nt][r] + bv + RES[idx];
    }
  }
}

extern "C" void kernel_launch(void* const* d_in, const int* in_sizes, int n_in,
                              void* d_out, int out_size, void* d_ws, size_t ws_size,
                              hipStream_t stream){
  const float* q_feat = (const float*)d_in[0];
  const float* kv_feat= (const float*)d_in[1];
  const float* gn_w   = (const float*)d_in[2];
  const float* gn_b   = (const float*)d_in[3];
  const float* wq     = (const float*)d_in[4];
  const float* bq     = (const float*)d_in[5];
  const float* wk     = (const float*)d_in[6];
  const float* bk     = (const float*)d_in[7];
  const float* wv     = (const float*)d_in[8];
  const float* bv     = (const float*)d_in[9];
  const float* wo     = (const float*)d_in[10];
  const float* bo     = (const float*)d_in[11];
  float* out = (float*)d_out;

  char* ws = (char*)d_ws;
  float* mu = (float*)ws;
  float* rs = (float*)(ws + 512);
  const size_t HSZ = (size_t)32 * N_PIX * DPAD;     // elements per head-layout buffer
  short* qh   = (short*)(ws + 4096);
  short* kh   = qh + HSZ;
  short* vt   = kh + HSZ;
  short* aout = vt + HSZ;                            // [B*N, 384] bf16

  // zero q/k/v head buffers (pad columns/rows must be 0; ws is poisoned each run)
  hipMemsetAsync(qh, 0, HSZ * 3 * sizeof(short), stream);

  gn_stats<<<128, 256, 0, stream>>>(q_feat, mu, rs);

  dim3 gp(36, 6, 4);
  proj_qk<<<gp, 256, 0, stream>>>(q_feat, wq, bq, gn_w, gn_b, mu, rs, qh, 1);
  proj_qk<<<gp, 256, 0, stream>>>(kv_feat, wk, bk, gn_w, gn_b, mu, rs, kh, 0);
  proj_v <<<gp, 256, 0, stream>>>(kv_feat, wv, bv, vt);

  attn_kernel<<<dim3(36, 32), 256, 0, stream>>>(qh, kh, vt, aout);

  proj_o<<<dim3(36, 4, 4), 256, 0, stream>>>(wo, bo, aout, q_feat, out);
}

// Round 7
// 290.603 us; speedup vs baseline: 1.4732x; 1.4732x over previous
//
#include <hip/hip_runtime.h>
#include <hip/hip_bf16.h>

#define N_PIX 2304
#define C_IN  256
#define INNER 384
#define HEADS 8
#define HDIM  48
#define DPAD  64
// attention scale folded with log2(e): softmax runs in exp2 domain
#define QSCALE (0.14433756729740643f * 1.44269504088896341f)

typedef __bf16 bf16x8 __attribute__((ext_vector_type(8)));
typedef float  f32x4  __attribute__((ext_vector_type(4)));
typedef short  s16x8  __attribute__((ext_vector_type(8)));

union Frag { s16x8 s; bf16x8 b; uint2 u[2]; };

__device__ inline short f2bf_bits(float f){
  union { float f; unsigned u; } v; v.f = f;
  unsigned r = v.u + 0x7fffu + ((v.u >> 16) & 1u);
  return (short)(r >> 16);
}

__device__ inline unsigned cvt_pk(float a, float b){
  unsigned r; asm("v_cvt_pk_bf16_f32 %0, %1, %2" : "=v"(r) : "v"(a), "v"(b));
  return r;
}

// ---------------- GroupNorm stats: one block per (b,g) ----------------
__global__ __launch_bounds__(256) void gn_stats(const float* __restrict__ x,
                                                float* __restrict__ mu,
                                                float* __restrict__ rs){
  int bg = blockIdx.x;
  const float* p = x + (size_t)bg * 8 * N_PIX;
  float s = 0.f, s2 = 0.f;
  for (int i = threadIdx.x; i < 8 * N_PIX; i += 256){
    float v = p[i]; s += v; s2 += v * v;
  }
  __shared__ float ls[256], ls2[256];
  ls[threadIdx.x] = s; ls2[threadIdx.x] = s2;
  __syncthreads();
  for (int off = 128; off > 0; off >>= 1){
    if ((int)threadIdx.x < off){ ls[threadIdx.x] += ls[threadIdx.x + off]; ls2[threadIdx.x] += ls2[threadIdx.x + off]; }
    __syncthreads();
  }
  if (threadIdx.x == 0){
    float m = ls[0] / 18432.f;
    float var = ls2[0] / 18432.f - m * m;
    mu[bg] = m; rs[bg] = rsqrtf(var + 1e-5f);
  }
}

// ---------------- weights f32 -> bf16 (wq|wk|wv|wo concatenated) ----------------
__global__ __launch_bounds__(256) void wconv(const float* __restrict__ a, const float* __restrict__ b,
                                             const float* __restrict__ c, const float* __restrict__ d,
                                             short* __restrict__ dst){
  int i = (blockIdx.x * 256 + threadIdx.x) * 8;   // 192 blocks * 2048 = 393216
  const float* src;
  if (i < 98304) src = a + i;
  else if (i < 196608) src = b + (i - 98304);
  else if (i < 294912) src = c + (i - 196608);
  else src = d + (i - 294912);
  float4 v0 = *(const float4*)src;
  float4 v1 = *(const float4*)(src + 4);
  uint4 o;
  o.x = cvt_pk(v0.x, v0.y); o.y = cvt_pk(v0.z, v0.w);
  o.z = cvt_pk(v1.x, v1.y); o.w = cvt_pk(v1.z, v1.w);
  *(uint4*)(dst + i) = o;
}

// ------- transpose [b,c,n] f32 -> [b,n,c] bf16, GN folded for q (which==0) -------
__global__ __launch_bounds__(256) void prep_x(const float* __restrict__ Xq, const float* __restrict__ Xkv,
                                              const float* __restrict__ gnw, const float* __restrict__ gnb,
                                              const float* __restrict__ mu, const float* __restrict__ rs,
                                              short* __restrict__ XTq, short* __restrict__ XTkv){
  int which = blockIdx.z >> 2;
  int b = blockIdx.z & 3;
  int nb = blockIdx.x * 64, cb = blockIdx.y * 64;
  const float* X = which ? Xkv : Xq;
  short* XT = which ? XTkv : XTq;
  __shared__ __align__(16) short lt[64][68];      // pad 68 -> row shifts 2 banks
  int t = threadIdx.x;
  int c_l = t >> 4, n4 = (t & 15) * 4;
  #pragma unroll
  for (int i = 0; i < 4; ++i){
    int cl = c_l + i * 16, c = cb + cl;
    float4 v = *(const float4*)(X + ((size_t)b * C_IN + c) * N_PIX + nb + n4);
    if (which == 0){
      int bg = b * 32 + (c >> 3);
      float w = gnw[c] * rs[bg], bb = gnb[c] - mu[bg] * w;
      v.x = v.x * w + bb; v.y = v.y * w + bb; v.z = v.z * w + bb; v.w = v.w * w + bb;
    }
    uint2 p; p.x = cvt_pk(v.x, v.y); p.y = cvt_pk(v.z, v.w);
    *(uint2*)&lt[cl][n4] = p;
  }
  __syncthreads();
  #pragma unroll
  for (int i = 0; i < 2; ++i){
    int idx = t + i * 256;
    int n = idx >> 3, c8 = (idx & 7) * 8;
    s16x8 o;
    #pragma unroll
    for (int j = 0; j < 8; ++j) o[j] = lt[c8 + j][n];
    *(s16x8*)(XT + ((size_t)b * N_PIX + nb + n) * C_IN + cb + c8) = o;
  }
}

// ---- Q/K projection: D[n][o], A=XT rows (contig), B=W rows (contig). OUT[b,h,n,64] ----
__global__ __launch_bounds__(256) void proj_qk(const short* __restrict__ XT,
                                               const short* __restrict__ WB,
                                               const float* __restrict__ bias,
                                               short* __restrict__ OUT, float scale){
  int b = blockIdx.z, nb = blockIdx.x * 64, ob = blockIdx.y * 64;
  int wave = threadIdx.x >> 6, lane = threadIdx.x & 63;
  int l16 = lane & 15, lq = lane >> 4;
  int o0 = ob + wave * 16;

  f32x4 acc[4] = {};
  const short* xbase = XT + ((size_t)b * N_PIX + nb) * C_IN;
  #pragma unroll
  for (int k = 0; k < 8; ++k){
    Frag wf; wf.s = *(const s16x8*)(WB + (size_t)(o0 + l16) * C_IN + k * 32 + lq * 8);
    #pragma unroll
    for (int nt = 0; nt < 4; ++nt){
      Frag af; af.s = *(const s16x8*)(xbase + (size_t)(nt * 16 + l16) * C_IN + k * 32 + lq * 8);
      acc[nt] = __builtin_amdgcn_mfma_f32_16x16x32_bf16(af.b, wf.b, acc[nt], 0, 0, 0);
    }
  }
  int o = o0 + l16;
  int h = (o * 683) >> 15, d = o - h * 48;
  float bv = bias[o];
  #pragma unroll
  for (int nt = 0; nt < 4; ++nt)
    #pragma unroll
    for (int r = 0; r < 4; ++r){
      int n = nb + nt * 16 + lq * 4 + r;
      OUT[(((size_t)b * HEADS + h) * N_PIX + n) * DPAD + d] = f2bf_bits((acc[nt][r] + bv) * scale);
    }

  if (ob == 0){                                   // zero pad cols d=48..63 (Q pad MUST be 0)
    s16x8 z = {0,0,0,0,0,0,0,0};
    for (int i = threadIdx.x; i < 1024; i += 256){
      int n = nb + (i >> 4);
      int hh = (i >> 1) & 7;
      int dd = 48 + (i & 1) * 8;
      *(s16x8*)(OUT + (((size_t)b * HEADS + hh) * N_PIX + n) * DPAD + dd) = z;
    }
  }
}

// ---- V projection: D[o][n], A=W rows (contig), B=XT rows as cols (contig). VT[b,h,d,n] ----
__global__ __launch_bounds__(256) void proj_v(const short* __restrict__ XT,
                                              const short* __restrict__ WB,
                                              const float* __restrict__ bias,
                                              short* __restrict__ VT){
  int b = blockIdx.z, nb = blockIdx.x * 64, ob = blockIdx.y * 64;
  int wave = threadIdx.x >> 6, lane = threadIdx.x & 63;
  int l16 = lane & 15, lq = lane >> 4;
  int o0 = ob + wave * 16;

  f32x4 acc[4] = {};
  const short* xbase = XT + ((size_t)b * N_PIX + nb) * C_IN;
  #pragma unroll
  for (int k = 0; k < 8; ++k){
    Frag wf; wf.s = *(const s16x8*)(WB + (size_t)(o0 + l16) * C_IN + k * 32 + lq * 8);
    #pragma unroll
    for (int nt = 0; nt < 4; ++nt){
      Frag xf; xf.s = *(const s16x8*)(xbase + (size_t)(nt * 16 + l16) * C_IN + k * 32 + lq * 8);
      acc[nt] = __builtin_amdgcn_mfma_f32_16x16x32_bf16(wf.b, xf.b, acc[nt], 0, 0, 0);
    }
  }
  #pragma unroll
  for (int r = 0; r < 4; ++r){
    int o = o0 + lq * 4 + r;
    int h = (o * 683) >> 15, d = o - h * 48;
    float bv = bias[o];
    #pragma unroll
    for (int nt = 0; nt < 4; ++nt){
      int n = nb + nt * 16 + l16;
      VT[(((size_t)b * HEADS + h) * DPAD + d) * N_PIX + n] = f2bf_bits(acc[nt][r] + bv);
    }
  }
}

// -------- Flash attention, swapped operands: lane-local softmax state --------
// S^T = mfma(K, Q): lane q=l16 holds S[q][j] for j = ct*16 + lq*4 + r (16 vals in-lane,
// partners at lanes ^16/^32).  O^T = mfma(VT, P): col=q, row=d.
__global__ __launch_bounds__(256) void attn_kernel(const short* __restrict__ Q,
                                                   const short* __restrict__ K,
                                                   const short* __restrict__ VT,
                                                   short* __restrict__ AOUT){
  int bh = blockIdx.y;
  int b = bh >> 3, h = bh & 7;
  int ib = blockIdx.x * 64;
  int wave = threadIdx.x >> 6, lane = threadIdx.x & 63;
  int l16 = lane & 15, lq = lane >> 4;
  int q0 = ib + wave * 16;

  __shared__ __align__(16) short kt[64 * 64];     // K tile [j][d], XOR-swizzled
  __shared__ __align__(16) short vt[64 * 64];     // V tile [d][j], XOR-swizzled
  __shared__ __align__(16) short pt[4][16 * 64];  // per-wave P [q][j], 4-short-block swizzle

  Frag qf[2];
  {
    const short* qp = Q + ((size_t)bh * N_PIX + q0 + l16) * DPAD + lq * 8;
    qf[0].s = *(const s16x8*)(qp);
    qf[1].s = *(const s16x8*)(qp + 32);
  }

  float m = -1e30f, l = 0.f;
  f32x4 oacc[3] = {};
  short* pw = &pt[wave][0];

  for (int jt = 0; jt < N_PIX / 64; ++jt){
    __syncthreads();
    #pragma unroll
    for (int it = 0; it < 2; ++it){
      int idx = threadIdx.x + it * 256;
      int row = idx >> 3, cb = idx & 7;
      int scb = cb ^ (row & 7);
      *(s16x8*)(kt + row * 64 + scb * 8) =
        *(const s16x8*)(K + ((size_t)bh * N_PIX + jt * 64 + row) * DPAD + cb * 8);
      *(s16x8*)(vt + row * 64 + scb * 8) =
        *(const s16x8*)(VT + ((size_t)bh * DPAD + row) * N_PIX + jt * 64 + cb * 8);
    }
    __syncthreads();

    // S^T tiles: D[row=j][col=q]
    f32x4 sc[4] = {};
    #pragma unroll
    for (int ct = 0; ct < 4; ++ct){
      int jr = ct * 16 + l16;
      #pragma unroll
      for (int kk = 0; kk < 2; ++kk){
        Frag kf;
        kf.s = *(const s16x8*)(kt + jr * 64 + ((kk * 4 + lq) ^ (jr & 7)) * 8);
        sc[ct] = __builtin_amdgcn_mfma_f32_16x16x32_bf16(kf.b, qf[kk].b, sc[ct], 0, 0, 0);
      }
    }

    // lane-local online softmax (q = l16; reduce across lanes ^16,^32)
    float mx = fmaxf(
      fmaxf(fmaxf(fmaxf(sc[0][0], sc[0][1]), fmaxf(sc[0][2], sc[0][3])),
            fmaxf(fmaxf(sc[1][0], sc[1][1]), fmaxf(sc[1][2], sc[1][3]))),
      fmaxf(fmaxf(fmaxf(sc[2][0], sc[2][1]), fmaxf(sc[2][2], sc[2][3])),
            fmaxf(fmaxf(sc[3][0], sc[3][1]), fmaxf(sc[3][2], sc[3][3]))));
    mx = fmaxf(mx, __shfl_xor(mx, 16));
    mx = fmaxf(mx, __shfl_xor(mx, 32));
    float mnew = fmaxf(m, mx);
    float corr = __builtin_amdgcn_exp2f(m - mnew);
    m = mnew;
    float ps = 0.f;
    #pragma unroll
    for (int ct = 0; ct < 4; ++ct)
      #pragma unroll
      for (int r = 0; r < 4; ++r){
        float p = __builtin_amdgcn_exp2f(sc[ct][r] - mnew);
        sc[ct][r] = p; ps += p;
      }
    ps += __shfl_xor(ps, 16);
    ps += __shfl_xor(ps, 32);
    l = l * corr + ps;
    #pragma unroll
    for (int dt = 0; dt < 3; ++dt)
      #pragma unroll
      for (int r = 0; r < 4; ++r) oacc[dt][r] *= corr;

    // P -> per-wave LDS: 4 consecutive j per lane -> cvt_pk pairs, b64 writes
    #pragma unroll
    for (int ct = 0; ct < 4; ++ct){
      uint2 p; p.x = cvt_pk(sc[ct][0], sc[ct][1]); p.y = cvt_pk(sc[ct][2], sc[ct][3]);
      *(uint2*)(pw + l16 * 64 + (((ct * 4 + lq) ^ l16) * 4)) = p;
    }

    // O^T += VT * P^T
    #pragma unroll
    for (int kk = 0; kk < 2; ++kk){
      Frag pf;
      pf.u[0] = *(const uint2*)(pw + l16 * 64 + ((((kk * 8 + lq * 2)    ) ^ l16) * 4));
      pf.u[1] = *(const uint2*)(pw + l16 * 64 + ((((kk * 8 + lq * 2) + 1) ^ l16) * 4));
      #pragma unroll
      for (int dt = 0; dt < 3; ++dt){
        int vr = dt * 16 + l16;
        Frag vf;
        vf.s = *(const s16x8*)(vt + vr * 64 + ((kk * 4 + lq) ^ (vr & 7)) * 8);
        oacc[dt] = __builtin_amdgcn_mfma_f32_16x16x32_bf16(vf.b, pf.b, oacc[dt], 0, 0, 0);
      }
    }
  }

  float inv = 1.f / l;
  short* op = AOUT + ((size_t)b * N_PIX + q0 + l16) * INNER + h * HDIM + lq * 4;
  #pragma unroll
  for (int dt = 0; dt < 3; ++dt){
    uint2 w;
    w.x = cvt_pk(oacc[dt][0] * inv, oacc[dt][1] * inv);
    w.y = cvt_pk(oacc[dt][2] * inv, oacc[dt][3] * inv);
    *(uint2*)(op + dt * 16) = w;
  }
}

// ---- Output projection + bias + residual: D[o][n]; both frags contiguous bf16 ----
__global__ __launch_bounds__(256) void proj_o(const short* __restrict__ WOB,
                                              const float* __restrict__ BO,
                                              const short* __restrict__ AOUT,
                                              const float* __restrict__ RES,
                                              float* __restrict__ OUT){
  int b = blockIdx.z, nb = blockIdx.x * 64, ob = blockIdx.y * 64;
  int wave = threadIdx.x >> 6, lane = threadIdx.x & 63;
  int l16 = lane & 15, lq = lane >> 4;
  int o0 = ob + wave * 16;

  f32x4 acc[4] = {};
  const short* abase = AOUT + ((size_t)b * N_PIX + nb) * INNER;
  #pragma unroll
  for (int k = 0; k < 12; ++k){
    Frag wf; wf.s = *(const s16x8*)(WOB + (size_t)(o0 + l16) * INNER + k * 32 + lq * 8);
    #pragma unroll
    for (int nt = 0; nt < 4; ++nt){
      Frag af; af.s = *(const s16x8*)(abase + (size_t)(nt * 16 + l16) * INNER + k * 32 + lq * 8);
      acc[nt] = __builtin_amdgcn_mfma_f32_16x16x32_bf16(wf.b, af.b, acc[nt], 0, 0, 0);
    }
  }
  #pragma unroll
  for (int r = 0; r < 4; ++r){
    int o = o0 + lq * 4 + r;
    float bv = BO[o];
    #pragma unroll
    for (int nt = 0; nt < 4; ++nt){
      int n = nb + nt * 16 + l16;
      size_t idx = ((size_t)b * C_IN + o) * N_PIX + n;
      OUT[idx] = acc[nt][r] + bv + RES[idx];
    }
  }
}

extern "C" void kernel_launch(void* const* d_in, const int* in_sizes, int n_in,
                              void* d_out, int out_size, void* d_ws, size_t ws_size,
                              hipStream_t stream){
  const float* q_feat = (const float*)d_in[0];
  const float* kv_feat= (const float*)d_in[1];
  const float* gn_w   = (const float*)d_in[2];
  const float* gn_b   = (const float*)d_in[3];
  const float* wq     = (const float*)d_in[4];
  const float* bq     = (const float*)d_in[5];
  const float* wk     = (const float*)d_in[6];
  const float* bk     = (const float*)d_in[7];
  const float* wv     = (const float*)d_in[8];
  const float* bv     = (const float*)d_in[9];
  const float* wo     = (const float*)d_in[10];
  const float* bo     = (const float*)d_in[11];
  float* out = (float*)d_out;

  char* ws = (char*)d_ws;
  float* mu = (float*)ws;
  float* rs = (float*)(ws + 512);
  short* wbf  = (short*)(ws + 4096);                    // 393216 shorts: wq|wk|wv|wo
  short* xtq  = (short*)(ws + 790528);                  // [b,n,256] bf16 (GN'd q)
  short* xtkv = (short*)(ws + 5509120);                 // [b,n,256] bf16
  short* qh   = (short*)(ws + 10227712);                // [b,h,n,64]
  short* kh   = (short*)(ws + 19664896);                // [b,h,n,64]
  short* vtb  = (short*)(ws + 29102080);                // [b,h,64,n]
  short* aout = (short*)(ws + 790528);                  // aliases xtq/xtkv (dead by attn)

  gn_stats<<<128, 256, 0, stream>>>(q_feat, mu, rs);
  wconv<<<192, 256, 0, stream>>>(wq, wk, wv, wo, wbf);
  prep_x<<<dim3(36, 4, 8), 256, 0, stream>>>(q_feat, kv_feat, gn_w, gn_b, mu, rs, xtq, xtkv);

  proj_qk<<<dim3(36, 6, 4), 256, 0, stream>>>(xtq,  wbf,          bq, qh, (float)QSCALE);
  proj_qk<<<dim3(36, 6, 4), 256, 0, stream>>>(xtkv, wbf + 98304,  bk, kh, 1.0f);
  proj_v <<<dim3(36, 6, 4), 256, 0, stream>>>(xtkv, wbf + 196608, bv, vtb);

  attn_kernel<<<dim3(36, 32), 256, 0, stream>>>(qh, kh, vtb, aout);

  proj_o<<<dim3(36, 4, 4), 256, 0, stream>>>(wbf + 294912, bo, aout, q_feat, out);
}